// Round 1
// baseline (582.889 us; speedup 1.0000x reference)
//
#include <hip/hip_runtime.h>

#define N_NODES 100000
#define N_EDGES 3200000
#define F_IN 128
#define F_OUT 16

#define NSEG 512                 // binning segments
#define EPS (N_EDGES / NSEG)     // 6250 edges/segment (exact)
#define NBUCK 512                // destination buckets
#define NPB 196                  // nodes per bucket: 196*512 = 100352 >= N
#define GEMM_BLOCKS ((N_NODES + 15) / 16)   // 6250
#define CLMASK 255               // c_local fits 8 bits (NPB=196)

// ---- ws layout (bytes) ----
// Tt (NBUCK*NSEG ints = 1 MB) ALIASES the g region (g written only in k_prep,
// strictly after k_bin's last Tt read). g is bf16 (ushort): 3.2 MB.
#define OFF_WSUM  0u            // N floats (400 KB): degree weight sums (init 1.0)
#define OFF_TOT   0x200000u     // NBUCK ints
#define OFF_BASE  0x202000u     // NBUCK ints
#define OFF_DINV  0x210000u     // N floats (400 KB)
#define OFF_HH    0x300000u     // N*16 floats (6.4 MB)
#define OFF_GG    0x920000u     // N*16 ushorts (3.2 MB), bf16
#define OFF_TT    0x920000u     // aliases GG (1 MB < 3.2 MB)
#define OFF_CSR   0x1000000u    // E int2 (25.6 MB), bucket-grouped (NOT node-sorted)
#define WS_NEEDED ((size_t)0x1000000 + (size_t)N_EDGES * 8)

__device__ __forceinline__ unsigned short f2bf(float f) {
    unsigned u = __float_as_uint(f);
    unsigned r = (u + 0x7FFFu + ((u >> 16) & 1u)) >> 16;   // RNE
    return (unsigned short)r;
}
__device__ __forceinline__ float bf2f(unsigned short v) {
    return __uint_as_float((unsigned)v << 16);
}

// ============ main path ============

// K0: wsum = 1.0 (self-loop weight) before K1's global atomics
__global__ void k_init(float* __restrict__ wsum) {
    int i = blockIdx.x * 256 + threadIdx.x;
    if (i < N_NODES) wsum[i] = 1.0f;
}

// K1: per-segment LDS histogram of dest buckets + global wsum atomics
//     + co-scheduled h = x@W
__global__ void k_hist_gemm(const int* __restrict__ col,
                            const float* __restrict__ ew,
                            int* __restrict__ Tt,
                            float* __restrict__ wsum,
                            const float* __restrict__ x,
                            const float* __restrict__ W,
                            float* __restrict__ h) {
    __shared__ int smem[2048];   // hist bins (512 used) OR 8KB W staging
    int tid = threadIdx.x;
    if (blockIdx.x < NSEG) {
        int s = blockIdx.x;
        for (int i = tid; i < NBUCK; i += 256) smem[i] = 0;
        __syncthreads();
        int e0 = s * EPS;
        for (int i = tid; i < EPS; i += 256) {
            int c = col[e0 + i];
            atomicAdd(&smem[c / NPB], 1);
            atomicAdd(&wsum[c], ew[e0 + i]);   // device-scope, fire-and-forget
        }
        __syncthreads();
        for (int i = tid; i < NBUCK; i += 256)
            Tt[(size_t)i * NSEG + s] = smem[i];
    } else {
        float* Ws = (float*)smem;
        for (int i = tid; i < F_IN * F_OUT; i += 256) Ws[i] = W[i];
        __syncthreads();
        int n = (blockIdx.x - NSEG) * 16 + (tid >> 4);
        int j = tid & 15;
        if (n >= N_NODES) return;
        const float4* xr = (const float4*)(x + (size_t)n * F_IN);
        float acc = 0.0f;
#pragma unroll
        for (int k4 = 0; k4 < F_IN / 4; ++k4) {
            float4 xv = xr[k4];
            int k = k4 * 4;
            acc += xv.x * Ws[(k + 0) * F_OUT + j];
            acc += xv.y * Ws[(k + 1) * F_OUT + j];
            acc += xv.z * Ws[(k + 2) * F_OUT + j];
            acc += xv.w * Ws[(k + 3) * F_OUT + j];
        }
        h[(size_t)n * F_OUT + j] = acc;
    }
}

// K2: wave per bucket — exclusive scan of its NSEG=512 counts
__global__ void k_scan_a(int* __restrict__ Tt, int* __restrict__ tot) {
    int tid = threadIdx.x;
    int b = blockIdx.x * 4 + (tid >> 6);
    int l = tid & 63;
    int4* row = (int4*)Tt + (size_t)b * (NSEG / 4);
    int4 v0 = row[l];
    int4 v1 = row[l + 64];
    int s0 = v0.x + v0.y + v0.z + v0.w;
    int inc0 = s0;
    for (int off = 1; off < 64; off <<= 1) {
        int t = __shfl_up(inc0, off);
        if (l >= off) inc0 += t;
    }
    int exc0 = inc0 - s0;
    int tot0 = __shfl(inc0, 63);
    int s1 = v1.x + v1.y + v1.z + v1.w;
    int inc1 = s1;
    for (int off = 1; off < 64; off <<= 1) {
        int t = __shfl_up(inc1, off);
        if (l >= off) inc1 += t;
    }
    int exc1 = inc1 - s1 + tot0;
    int4 o0, o1;
    o0.x = exc0;
    o0.y = exc0 + v0.x;
    o0.z = o0.y + v0.y;
    o0.w = o0.z + v0.z;
    o1.x = exc1;
    o1.y = exc1 + v1.x;
    o1.z = o1.y + v1.y;
    o1.w = o1.z + v1.z;
    row[l] = o0;
    row[l + 64] = o1;
    if (l == 63) tot[b] = inc1 + tot0;
}

// K3: single block — exclusive scan of NBUCK=512 totals -> base
__global__ void k_scan_b(const int* __restrict__ tot, int* __restrict__ base) {
    __shared__ int s[256];
    int tid = threadIdx.x;
    const int4* t4 = (const int4*)tot;
    int4 p = (tid < NBUCK / 4) ? t4[tid] : make_int4(0, 0, 0, 0);
    int lsum = p.x + p.y + p.z + p.w;
    s[tid] = lsum;
    __syncthreads();
    for (int off = 1; off < 256; off <<= 1) {
        int t = (tid >= off) ? s[tid - off] : 0;
        __syncthreads();
        s[tid] += t;
        __syncthreads();
    }
    int run = s[tid] - lsum;
    if (tid < NBUCK / 4) {
        int4 o;
        o.x = run; run += p.x;
        o.y = run; run += p.y;
        o.z = run; run += p.z;
        o.w = run;
        ((int4*)base)[tid] = o;
    }
}

// K4: rank-and-write binning: hist -> scan -> rank into LDS -> linear write-out
__global__ void __launch_bounds__(512) k_bin(const int* __restrict__ row,
                                             const int* __restrict__ col,
                                             const float* __restrict__ ew,
                                             const int* __restrict__ Tt,
                                             const int* __restrict__ base,
                                             int2* __restrict__ csr) {
    __shared__ int2 srec[EPS];        // 50000 B
    __shared__ int lcnt[NBUCK];
    __shared__ int lpre[NBUCK + 1];
    __shared__ int gofs[NBUCK];
    int tid = threadIdx.x;
    int s = blockIdx.x;
    int e0 = s * EPS;

    lcnt[tid] = 0;
    __syncthreads();
    for (int i = tid; i < EPS; i += 512)
        atomicAdd(&lcnt[col[e0 + i] / NPB], 1);
    __syncthreads();

    int v = lcnt[tid];
    gofs[tid] = v;
    __syncthreads();
    for (int off = 1; off < 512; off <<= 1) {
        int t = (tid >= off) ? gofs[tid - off] : 0;
        __syncthreads();
        gofs[tid] += t;
        __syncthreads();
    }
    int excl = gofs[tid] - v;
    lpre[tid] = excl;
    if (tid == 0) lpre[NBUCK] = EPS;
    __syncthreads();
    gofs[tid] = base[tid] + Tt[(size_t)tid * NSEG + s] - excl;
    lcnt[tid] = excl;
    __syncthreads();

    for (int i = tid; i < EPS; i += 512) {
        int e = e0 + i;
        int r = row[e];
        int c = col[e];
        int bk = c / NPB;
        int pos = atomicAdd(&lcnt[bk], 1);     // LDS atomic
        int2 rec;
        rec.x = (r << 8) | (c - bk * NPB);
        rec.y = __float_as_int(ew[e]);
        srec[pos] = rec;
    }
    __syncthreads();

    for (int t = tid; t < EPS; t += 512) {
        int lo = 0, hi = NBUCK;
        while (hi - lo > 1) {
            int mid = (lo + hi) >> 1;
            if (lpre[mid] <= t) lo = mid; else hi = mid;
        }
        csr[gofs[lo] + t] = srec[t];
    }
}

// K5: streaming — dinv = rsqrt(wsum); g = bf16(dinv*h). (After k_bin: gb aliases Tt.)
__global__ void k_prep(const float* __restrict__ wsum,
                       const float* __restrict__ h,
                       float* __restrict__ dinv,
                       unsigned short* __restrict__ gb) {
    int t = blockIdx.x * 256 + threadIdx.x;     // one 4-element group
    if (t >= N_NODES * 4) return;
    int n = t >> 2;
    float d = rsqrtf(wsum[n]);
    if ((t & 3) == 0) dinv[n] = d;
    float4 hv = ((const float4*)h)[t];
    unsigned o0 = (unsigned)f2bf(d * hv.x) | ((unsigned)f2bf(d * hv.y) << 16);
    unsigned o1 = (unsigned)f2bf(d * hv.z) | ((unsigned)f2bf(d * hv.w) << 16);
    uint2 o; o.x = o0; o.y = o1;
    ((uint2*)gb)[t] = o;
}

// K6: bucket per block — stream unsorted bucket records, accumulate into
// LDS fp32 acc[NPB][F_OUT] via ds_add_f32; coalesced epilogue write.
// No sort, no nodeptr/ncnt, no overflow path.
__global__ void __launch_bounds__(1024) k_agg(const int* __restrict__ base,
                                              const int* __restrict__ tot,
                                              const int2* __restrict__ csr,
                                              const unsigned short* __restrict__ gb,
                                              const float* __restrict__ dinv,
                                              const float* __restrict__ bias,
                                              float* __restrict__ out) {
    __shared__ float acc[NPB * F_OUT];   // 12544 B
    int tid = threadIdx.x;
    int b = blockIdx.x;
    int c0 = b * NPB;
    for (int i = tid; i < NPB * F_OUT; i += 1024) acc[i] = 0.0f;
    __syncthreads();

    int bseg = base[b];
    int total = tot[b];
    int g16 = tid >> 4;      // 0..63 record groups
    int j = tid & 15;
#pragma unroll 4
    for (int i = g16; i < total; i += 64) {
        int2 rec = csr[bseg + i];                 // broadcast within 16-lane group
        float v = bf2f(gb[(size_t)(rec.x >> 8) * F_OUT + j]) * __int_as_float(rec.y);
        atomicAdd(&acc[(rec.x & CLMASK) * F_OUT + j], v);   // ds_add_f32
    }
    __syncthreads();

    for (int i = tid; i < NPB * F_OUT; i += 1024) {
        int n = c0 + (i >> 4);
        if (n < N_NODES) {
            int jj = i & 15;
            float d = dinv[n];
            float gs = bf2f(gb[(size_t)n * F_OUT + jj]);    // self-loop term
            out[(size_t)n * F_OUT + jj] = bias[jj] + d * (gs + acc[i]);
        }
    }
}

// ============ fallback path (R4, proven; fp32 g) ============

#define EDGE_BLOCKS_FB ((N_EDGES + 255) / 256)
__global__ void k_init_fb(float* __restrict__ deg) {
    int i = blockIdx.x * blockDim.x + threadIdx.x;
    if (i < N_NODES) deg[i] = 1.0f;
}
__global__ void k_fused_fb(const int* __restrict__ col, const float* __restrict__ ew,
                           float* __restrict__ deg, const float* __restrict__ x,
                           const float* __restrict__ W, float* __restrict__ h) {
    int b3 = blockIdx.x / 3;
    int r3 = blockIdx.x % 3;
    if (r3 < 2) {
        int e = (b3 * 2 + r3) * 256 + threadIdx.x;
        if (e < N_EDGES) atomicAdd(&deg[col[e]], ew[e]);
    } else {
        __shared__ float Ws[F_IN * F_OUT];
        int tid = threadIdx.x;
        for (int i = tid; i < F_IN * F_OUT; i += 256) Ws[i] = W[i];
        __syncthreads();
        int n = b3 * 16 + (tid >> 4);
        int j = tid & 15;
        if (n >= N_NODES) return;
        const float4* xr = (const float4*)(x + (size_t)n * F_IN);
        float acc = 0.0f;
#pragma unroll
        for (int k4 = 0; k4 < F_IN / 4; ++k4) {
            float4 xv = xr[k4];
            int k = k4 * 4;
            acc += xv.x * Ws[(k + 0) * F_OUT + j];
            acc += xv.y * Ws[(k + 1) * F_OUT + j];
            acc += xv.z * Ws[(k + 2) * F_OUT + j];
            acc += xv.w * Ws[(k + 3) * F_OUT + j];
        }
        h[(size_t)n * F_OUT + j] = acc;
    }
}
__global__ void k_final_fb(float* __restrict__ deg, const float* __restrict__ h,
                           const float* __restrict__ b, float* __restrict__ g,
                           float* __restrict__ out) {
    int i = blockIdx.x * blockDim.x + threadIdx.x;
    int n = i >> 4;
    int j = i & 15;
    if (n >= N_NODES) return;
    float d = rsqrtf(deg[n]);
    if (j == 0) deg[n] = d;
    float gg = d * h[i];
    g[i] = gg;
    out[i] = b[j] + d * gg;
}
__global__ void k_scatter_fb(const int* __restrict__ row, const int* __restrict__ col,
                             const float* __restrict__ ew, const float* __restrict__ dinv,
                             const float* __restrict__ g, float* __restrict__ out) {
    long long tid = (long long)blockIdx.x * blockDim.x + threadIdx.x;
    int e = (int)(tid >> 4);
    int j = (int)(tid & 15);
    if (e >= N_EDGES) return;
    int c = col[e];
    float norm = ew[e] * dinv[c];
    atomicAdd(&out[(size_t)c * F_OUT + j], g[(size_t)row[e] * F_OUT + j] * norm);
}

extern "C" void kernel_launch(void* const* d_in, const int* in_sizes, int n_in,
                              void* d_out, int out_size, void* d_ws, size_t ws_size,
                              hipStream_t stream) {
    const float* x  = (const float*)d_in[0];
    const int*   ei = (const int*)d_in[1];   // [2, N_EDGES] int32
    const float* ew = (const float*)d_in[2];
    const float* W  = (const float*)d_in[3];
    const float* b  = (const float*)d_in[4];
    float* out = (float*)d_out;

    const int* row = ei;            // edge_index[0] = source
    const int* col = ei + N_EDGES;  // edge_index[1] = destination

    char* ws = (char*)d_ws;
    dim3 blk(256);

    if (ws_size >= WS_NEEDED) {
        float* wsum = (float*)(ws + OFF_WSUM);
        int*   tot  = (int*)(ws + OFF_TOT);
        int*   base = (int*)(ws + OFF_BASE);
        float* dinv = (float*)(ws + OFF_DINV);
        float* h    = (float*)(ws + OFF_HH);
        unsigned short* gb = (unsigned short*)(ws + OFF_GG);
        int*   Tt   = (int*)(ws + OFF_TT);      // aliases gb (dead before k_prep)
        int2*  csr  = (int2*)(ws + OFF_CSR);

        k_init<<<(N_NODES + 255) / 256, blk, 0, stream>>>(wsum);
        k_hist_gemm<<<NSEG + GEMM_BLOCKS, blk, 0, stream>>>(col, ew, Tt, wsum, x, W, h);
        k_scan_a<<<NBUCK / 4, blk, 0, stream>>>(Tt, tot);
        k_scan_b<<<1, blk, 0, stream>>>(tot, base);
        k_bin<<<NSEG, 512, 0, stream>>>(row, col, ew, Tt, base, csr);
        k_prep<<<(N_NODES * 4 + 255) / 256, blk, 0, stream>>>(wsum, h, dinv, gb);
        k_agg<<<NBUCK, 1024, 0, stream>>>(base, tot, csr, gb, dinv, b, out);
    } else {
        float* deg = (float*)ws;
        float* h   = (float*)(ws + (1u << 20));
        float* g   = (float*)(ws + (8u << 20));
        k_init_fb<<<(N_NODES + 255) / 256, blk, 0, stream>>>(deg);
        k_fused_fb<<<EDGE_BLOCKS_FB + GEMM_BLOCKS, blk, 0, stream>>>(col, ew, deg, x, W, h);
        k_final_fb<<<(N_NODES * F_OUT + 255) / 256, blk, 0, stream>>>(deg, h, b, g, out);
        long long total = (long long)N_EDGES * F_OUT;
        k_scatter_fb<<<(unsigned)((total + 255) / 256), blk, 0, stream>>>(row, col, ew, deg, g, out);
    }
}

// Round 3
// 464.372 us; speedup vs baseline: 1.2552x; 1.2552x over previous
//
#include <hip/hip_runtime.h>

#define N_NODES 100000
#define N_EDGES 3200000
#define F_IN 128
#define F_OUT 16

#define NSEG 512                 // binning segments
#define EPS (N_EDGES / NSEG)     // 6250 edges/segment (exact)
#define NBUCK 512                // destination buckets
#define NPB 196                  // nodes per bucket: 196*512 = 100352 >= N
#define GEMM_BLOCKS ((N_NODES + 15) / 16)   // 6250
#define CLMASK 255               // c_local fits 8 bits (NPB=196)

// ---- ws layout (bytes) ----
// Tt (NBUCK*NSEG ints = 1 MB) ALIASES the g region (g written only in k_prep,
// strictly after k_bin's last Tt read). g is bf16 (ushort): 3.2 MB.
#define OFF_TOT   0x200000u     // NBUCK ints
#define OFF_BASE  0x202000u     // NBUCK ints
#define OFF_DINV  0x210000u     // N floats (400 KB)
#define OFF_HH    0x300000u     // N*16 floats (6.4 MB)
#define OFF_GG    0x920000u     // N*16 ushorts (3.2 MB), bf16
#define OFF_TT    0x920000u     // aliases GG (1 MB < 3.2 MB)
#define OFF_CSR   0x1000000u    // E int2 (25.6 MB), bucket-grouped (NOT node-sorted)
#define WS_NEEDED ((size_t)0x1000000 + (size_t)N_EDGES * 8)

__device__ __forceinline__ unsigned short f2bf(float f) {
    unsigned u = __float_as_uint(f);
    unsigned r = (u + 0x7FFFu + ((u >> 16) & 1u)) >> 16;   // RNE
    return (unsigned short)r;
}
__device__ __forceinline__ float bf2f(unsigned short v) {
    return __uint_as_float((unsigned)v << 16);
}

// Native fire-and-forget fp32 LDS atomic (HIP atomicAdd on shared float
// lowered to a CAS loop -> the R1 270us k_agg disaster). Generic pointers to
// LDS carry the LDS byte offset in their low 32 bits on AMDGCN.
// NO memory clobber: csr loads may still batch ahead of these.
__device__ __forceinline__ void lds_fadd(float* p, float v) {
    unsigned a = (unsigned)(unsigned long long)p;
    asm volatile("ds_add_f32 %0, %1" : : "v"(a), "v"(v));
}
// R2 bug: these asm atomics are invisible to the memory legalizer, so
// __syncthreads() emitted s_barrier WITHOUT draining the DS queue ->
// a handful of lost updates (absmax 6.6e-2). Explicit drain before barrier.
__device__ __forceinline__ void lds_atomic_fence() {
    asm volatile("s_waitcnt lgkmcnt(0)" ::: "memory");
    __builtin_amdgcn_sched_barrier(0);
}

// ============ main path ============

// K1: per-segment LDS histogram of dest buckets + co-scheduled h = x@W
__global__ void k_hist_gemm(const int* __restrict__ col,
                            int* __restrict__ Tt,
                            const float* __restrict__ x,
                            const float* __restrict__ W,
                            float* __restrict__ h) {
    __shared__ int smem[2048];   // hist bins (512 used) OR 8KB W staging
    int tid = threadIdx.x;
    if (blockIdx.x < NSEG) {
        int s = blockIdx.x;
        for (int i = tid; i < NBUCK; i += 256) smem[i] = 0;
        __syncthreads();
        int e0 = s * EPS;
        for (int i = tid; i < EPS; i += 256)
            atomicAdd(&smem[col[e0 + i] / NPB], 1);
        __syncthreads();
        for (int i = tid; i < NBUCK; i += 256)
            Tt[(size_t)i * NSEG + s] = smem[i];
    } else {
        float* Ws = (float*)smem;
        for (int i = tid; i < F_IN * F_OUT; i += 256) Ws[i] = W[i];
        __syncthreads();
        int n = (blockIdx.x - NSEG) * 16 + (tid >> 4);
        int j = tid & 15;
        if (n >= N_NODES) return;
        const float4* xr = (const float4*)(x + (size_t)n * F_IN);
        float acc = 0.0f;
#pragma unroll
        for (int k4 = 0; k4 < F_IN / 4; ++k4) {
            float4 xv = xr[k4];
            int k = k4 * 4;
            acc += xv.x * Ws[(k + 0) * F_OUT + j];
            acc += xv.y * Ws[(k + 1) * F_OUT + j];
            acc += xv.z * Ws[(k + 2) * F_OUT + j];
            acc += xv.w * Ws[(k + 3) * F_OUT + j];
        }
        h[(size_t)n * F_OUT + j] = acc;
    }
}

// K2: wave per bucket — exclusive scan of its NSEG=512 counts
__global__ void k_scan_a(int* __restrict__ Tt, int* __restrict__ tot) {
    int tid = threadIdx.x;
    int b = blockIdx.x * 4 + (tid >> 6);
    int l = tid & 63;
    int4* row = (int4*)Tt + (size_t)b * (NSEG / 4);
    int4 v0 = row[l];
    int4 v1 = row[l + 64];
    int s0 = v0.x + v0.y + v0.z + v0.w;
    int inc0 = s0;
    for (int off = 1; off < 64; off <<= 1) {
        int t = __shfl_up(inc0, off);
        if (l >= off) inc0 += t;
    }
    int exc0 = inc0 - s0;
    int tot0 = __shfl(inc0, 63);
    int s1 = v1.x + v1.y + v1.z + v1.w;
    int inc1 = s1;
    for (int off = 1; off < 64; off <<= 1) {
        int t = __shfl_up(inc1, off);
        if (l >= off) inc1 += t;
    }
    int exc1 = inc1 - s1 + tot0;
    int4 o0, o1;
    o0.x = exc0;
    o0.y = exc0 + v0.x;
    o0.z = o0.y + v0.y;
    o0.w = o0.z + v0.z;
    o1.x = exc1;
    o1.y = exc1 + v1.x;
    o1.z = o1.y + v1.y;
    o1.w = o1.z + v1.z;
    row[l] = o0;
    row[l + 64] = o1;
    if (l == 63) tot[b] = inc1 + tot0;
}

// K3: single block — exclusive scan of NBUCK=512 totals -> base
__global__ void k_scan_b(const int* __restrict__ tot, int* __restrict__ base) {
    __shared__ int s[256];
    int tid = threadIdx.x;
    const int4* t4 = (const int4*)tot;
    int4 p = (tid < NBUCK / 4) ? t4[tid] : make_int4(0, 0, 0, 0);
    int lsum = p.x + p.y + p.z + p.w;
    s[tid] = lsum;
    __syncthreads();
    for (int off = 1; off < 256; off <<= 1) {
        int t = (tid >= off) ? s[tid - off] : 0;
        __syncthreads();
        s[tid] += t;
        __syncthreads();
    }
    int run = s[tid] - lsum;
    if (tid < NBUCK / 4) {
        int4 o;
        o.x = run; run += p.x;
        o.y = run; run += p.y;
        o.z = run; run += p.z;
        o.w = run;
        ((int4*)base)[tid] = o;
    }
}

// K4: rank-and-write binning: hist -> scan -> rank into LDS -> linear write-out
__global__ void __launch_bounds__(512) k_bin(const int* __restrict__ row,
                                             const int* __restrict__ col,
                                             const float* __restrict__ ew,
                                             const int* __restrict__ Tt,
                                             const int* __restrict__ base,
                                             int2* __restrict__ csr) {
    __shared__ int2 srec[EPS];        // 50000 B
    __shared__ int lcnt[NBUCK];
    __shared__ int lpre[NBUCK + 1];
    __shared__ int gofs[NBUCK];
    int tid = threadIdx.x;
    int s = blockIdx.x;
    int e0 = s * EPS;

    lcnt[tid] = 0;
    __syncthreads();
    for (int i = tid; i < EPS; i += 512)
        atomicAdd(&lcnt[col[e0 + i] / NPB], 1);
    __syncthreads();

    int v = lcnt[tid];
    gofs[tid] = v;
    __syncthreads();
    for (int off = 1; off < 512; off <<= 1) {
        int t = (tid >= off) ? gofs[tid - off] : 0;
        __syncthreads();
        gofs[tid] += t;
        __syncthreads();
    }
    int excl = gofs[tid] - v;
    lpre[tid] = excl;
    if (tid == 0) lpre[NBUCK] = EPS;
    __syncthreads();
    gofs[tid] = base[tid] + Tt[(size_t)tid * NSEG + s] - excl;
    lcnt[tid] = excl;
    __syncthreads();

    for (int i = tid; i < EPS; i += 512) {
        int e = e0 + i;
        int r = row[e];
        int c = col[e];
        int bk = c / NPB;
        int pos = atomicAdd(&lcnt[bk], 1);     // LDS int atomic (native)
        int2 rec;
        rec.x = (r << 8) | (c - bk * NPB);
        rec.y = __float_as_int(ew[e]);
        srec[pos] = rec;
    }
    __syncthreads();

    for (int t = tid; t < EPS; t += 512) {
        int lo = 0, hi = NBUCK;
        while (hi - lo > 1) {
            int mid = (lo + hi) >> 1;
            if (lpre[mid] <= t) lo = mid; else hi = mid;
        }
        csr[gofs[lo] + t] = srec[t];
    }
}

// K5: per-bucket — stream binned records once, LDS wsum via native ds_add_f32,
// then dinv = rsqrt(wsum), g = bf16(dinv*h). (After k_bin: gb aliases Tt.)
__global__ void k_prep(const int* __restrict__ base,
                       const int* __restrict__ tot,
                       const int2* __restrict__ csr,
                       const float* __restrict__ h,
                       float* __restrict__ dinv,
                       unsigned short* __restrict__ gb) {
    __shared__ float ws[256];
    __shared__ float dl[256];
    int tid = threadIdx.x;
    int b = blockIdx.x;
    int c0 = b * NPB;
    ws[tid] = 1.0f;      // self-loop weight
    __syncthreads();
    int bseg = base[b];
    int total = tot[b];
#pragma unroll 4
    for (int i = tid; i < total; i += 256) {
        int2 rec = csr[bseg + i];
        lds_fadd(&ws[rec.x & CLMASK], __int_as_float(rec.y));
    }
    lds_atomic_fence();
    __syncthreads();
    float d = rsqrtf(ws[tid]);
    dl[tid] = d;
    int n = c0 + tid;
    if (tid < NPB && n < N_NODES) dinv[n] = d;
    __syncthreads();
    for (int i = tid; i < NPB * F_OUT; i += 256) {
        int idx = c0 * F_OUT + i;
        if (idx < N_NODES * F_OUT) gb[idx] = f2bf(dl[i >> 4] * h[idx]);
    }
}

// K6: bucket per block — stream unsorted bucket records, accumulate into
// LDS fp32 acc[NPB][F_OUT] via native ds_add_f32; coalesced epilogue write.
__global__ void __launch_bounds__(1024) k_agg(const int* __restrict__ base,
                                              const int* __restrict__ tot,
                                              const int2* __restrict__ csr,
                                              const unsigned short* __restrict__ gb,
                                              const float* __restrict__ dinv,
                                              const float* __restrict__ bias,
                                              float* __restrict__ out) {
    __shared__ float acc[NPB * F_OUT];   // 12544 B
    int tid = threadIdx.x;
    int b = blockIdx.x;
    int c0 = b * NPB;
    for (int i = tid; i < NPB * F_OUT; i += 1024) acc[i] = 0.0f;
    __syncthreads();

    int bseg = base[b];
    int total = tot[b];
    int g16 = tid >> 4;      // 0..63 record groups
    int j = tid & 15;
#pragma unroll 4
    for (int i = g16; i < total; i += 64) {
        int2 rec = csr[bseg + i];                 // broadcast within 16-lane group
        float v = bf2f(gb[(size_t)(rec.x >> 8) * F_OUT + j]) * __int_as_float(rec.y);
        lds_fadd(&acc[(rec.x & CLMASK) * F_OUT + j], v);   // native ds_add_f32
    }
    lds_atomic_fence();
    __syncthreads();

    for (int i = tid; i < NPB * F_OUT; i += 1024) {
        int n = c0 + (i >> 4);
        if (n < N_NODES) {
            int jj = i & 15;
            float d = dinv[n];
            float gs = bf2f(gb[(size_t)n * F_OUT + jj]);    // self-loop term
            out[(size_t)n * F_OUT + jj] = bias[jj] + d * (gs + acc[i]);
        }
    }
}

// ============ fallback path (R4, proven; fp32 g) ============

#define EDGE_BLOCKS_FB ((N_EDGES + 255) / 256)
__global__ void k_init_fb(float* __restrict__ deg) {
    int i = blockIdx.x * blockDim.x + threadIdx.x;
    if (i < N_NODES) deg[i] = 1.0f;
}
__global__ void k_fused_fb(const int* __restrict__ col, const float* __restrict__ ew,
                           float* __restrict__ deg, const float* __restrict__ x,
                           const float* __restrict__ W, float* __restrict__ h) {
    int b3 = blockIdx.x / 3;
    int r3 = blockIdx.x % 3;
    if (r3 < 2) {
        int e = (b3 * 2 + r3) * 256 + threadIdx.x;
        if (e < N_EDGES) atomicAdd(&deg[col[e]], ew[e]);
    } else {
        __shared__ float Ws[F_IN * F_OUT];
        int tid = threadIdx.x;
        for (int i = tid; i < F_IN * F_OUT; i += 256) Ws[i] = W[i];
        __syncthreads();
        int n = b3 * 16 + (tid >> 4);
        int j = tid & 15;
        if (n >= N_NODES) return;
        const float4* xr = (const float4*)(x + (size_t)n * F_IN);
        float acc = 0.0f;
#pragma unroll
        for (int k4 = 0; k4 < F_IN / 4; ++k4) {
            float4 xv = xr[k4];
            int k = k4 * 4;
            acc += xv.x * Ws[(k + 0) * F_OUT + j];
            acc += xv.y * Ws[(k + 1) * F_OUT + j];
            acc += xv.z * Ws[(k + 2) * F_OUT + j];
            acc += xv.w * Ws[(k + 3) * F_OUT + j];
        }
        h[(size_t)n * F_OUT + j] = acc;
    }
}
__global__ void k_final_fb(float* __restrict__ deg, const float* __restrict__ h,
                           const float* __restrict__ b, float* __restrict__ g,
                           float* __restrict__ out) {
    int i = blockIdx.x * blockDim.x + threadIdx.x;
    int n = i >> 4;
    int j = i & 15;
    if (n >= N_NODES) return;
    float d = rsqrtf(deg[n]);
    if (j == 0) deg[n] = d;
    float gg = d * h[i];
    g[i] = gg;
    out[i] = b[j] + d * gg;
}
__global__ void k_scatter_fb(const int* __restrict__ row, const int* __restrict__ col,
                             const float* __restrict__ ew, const float* __restrict__ dinv,
                             const float* __restrict__ g, float* __restrict__ out) {
    long long tid = (long long)blockIdx.x * blockDim.x + threadIdx.x;
    int e = (int)(tid >> 4);
    int j = (int)(tid & 15);
    if (e >= N_EDGES) return;
    int c = col[e];
    float norm = ew[e] * dinv[c];
    atomicAdd(&out[(size_t)c * F_OUT + j], g[(size_t)row[e] * F_OUT + j] * norm);
}

extern "C" void kernel_launch(void* const* d_in, const int* in_sizes, int n_in,
                              void* d_out, int out_size, void* d_ws, size_t ws_size,
                              hipStream_t stream) {
    const float* x  = (const float*)d_in[0];
    const int*   ei = (const int*)d_in[1];   // [2, N_EDGES] int32
    const float* ew = (const float*)d_in[2];
    const float* W  = (const float*)d_in[3];
    const float* b  = (const float*)d_in[4];
    float* out = (float*)d_out;

    const int* row = ei;            // edge_index[0] = source
    const int* col = ei + N_EDGES;  // edge_index[1] = destination

    char* ws = (char*)d_ws;
    dim3 blk(256);

    if (ws_size >= WS_NEEDED) {
        int*   tot  = (int*)(ws + OFF_TOT);
        int*   base = (int*)(ws + OFF_BASE);
        float* dinv = (float*)(ws + OFF_DINV);
        float* h    = (float*)(ws + OFF_HH);
        unsigned short* gb = (unsigned short*)(ws + OFF_GG);
        int*   Tt   = (int*)(ws + OFF_TT);      // aliases gb (dead before k_prep)
        int2*  csr  = (int2*)(ws + OFF_CSR);

        k_hist_gemm<<<NSEG + GEMM_BLOCKS, blk, 0, stream>>>(col, Tt, x, W, h);
        k_scan_a<<<NBUCK / 4, blk, 0, stream>>>(Tt, tot);
        k_scan_b<<<1, blk, 0, stream>>>(tot, base);
        k_bin<<<NSEG, 512, 0, stream>>>(row, col, ew, Tt, base, csr);
        k_prep<<<NBUCK, blk, 0, stream>>>(base, tot, csr, h, dinv, gb);
        k_agg<<<NBUCK, 1024, 0, stream>>>(base, tot, csr, gb, dinv, b, out);
    } else {
        float* deg = (float*)ws;
        float* h   = (float*)(ws + (1u << 20));
        float* g   = (float*)(ws + (8u << 20));
        k_init_fb<<<(N_NODES + 255) / 256, blk, 0, stream>>>(deg);
        k_fused_fb<<<EDGE_BLOCKS_FB + GEMM_BLOCKS, blk, 0, stream>>>(col, ew, deg, x, W, h);
        k_final_fb<<<(N_NODES * F_OUT + 255) / 256, blk, 0, stream>>>(deg, h, b, g, out);
        long long total = (long long)N_EDGES * F_OUT;
        k_scatter_fb<<<(unsigned)((total + 255) / 256), blk, 0, stream>>>(row, col, ew, deg, g, out);
    }
}